// Round 5
// baseline (309.067 us; speedup 1.0000x reference)
//
#include <hip/hip_runtime.h>
#include <hip/hip_bf16.h>
#include <math.h>

#define HEADS 3
#define HO 384
#define NGRAPH 64
#define F_IN 256
#define SLOPE 0.2f

typedef __attribute__((ext_vector_type(8))) short bf8;
typedef __attribute__((ext_vector_type(4))) float f4;
typedef __attribute__((ext_vector_type(2))) unsigned u2v;
typedef __attribute__((ext_vector_type(4))) unsigned u4v;

// ---- bf16 helpers ----
__device__ __forceinline__ unsigned short bfr(float f) {
    unsigned u = __float_as_uint(f);
    u += 0x7fffu + ((u >> 16) & 1u);
    return (unsigned short)(u >> 16);
}
__device__ __forceinline__ float bflo(unsigned u) { return __uint_as_float(u << 16); }
__device__ __forceinline__ float bfhi(unsigned u) { return __uint_as_float(u & 0xffff0000u); }
__device__ __forceinline__ float lrelu(float v) { return (v > 0.f) ? v : SLOPE * v; }

// ---- biased-byte decode: bytes store q+128; v_perm builds half2(1024+b) (exact
// in f16), v_fma_mix_f32 accumulates wm*(1152+q) into f32 acc. The 1152*wsum
// offset is subtracted once in the epilogue. 12 insts per 8 channels. ----
__device__ __forceinline__ void mix2(float& a0, float& a1, unsigned h2, float wm) {
    asm("v_fma_mix_f32 %0, %2, %3, %0 op_sel:[0,0,0] op_sel_hi:[1,0,0]\n\t"
        "v_fma_mix_f32 %1, %2, %3, %1 op_sel:[1,0,0] op_sel_hi:[1,0,0]"
        : "+v"(a0), "+v"(a1)
        : "v"(h2), "v"(wm));
}
__device__ __forceinline__ void dec8_mix(float* acc, float wm, unsigned ux, unsigned uy,
                                         unsigned c64) {
    unsigned p0 = __builtin_amdgcn_perm(ux, c64, 0x00050004u); // [b0,0x64,b1,0x64]
    unsigned p1 = __builtin_amdgcn_perm(ux, c64, 0x00070006u);
    unsigned p2 = __builtin_amdgcn_perm(uy, c64, 0x00050004u);
    unsigned p3 = __builtin_amdgcn_perm(uy, c64, 0x00070006u);
    mix2(acc[0], acc[1], p0, wm);
    mix2(acc[2], acc[3], p1, wm);
    mix2(acc[4], acc[5], p2, wm);
    mix2(acc[6], acc[7], p3, wm);
}

// ---- K0: fused misc pre-pass (block-range dispatch):
//   [0, NBc)              : degree count + per-edge rank
//   [NBc, NBc+384)        : W -> WbT bf16 transpose-convert
//   NBc+384               : per-graph start offsets
//   (NBc+384, +NXc]       : X f32 -> Xb bf16 streaming convert (2048 elems/blk)
__global__ __launch_bounds__(256) void misc_k(const int* __restrict__ ei,
                                              const float* __restrict__ W,
                                              const int* __restrict__ batch,
                                              const float* __restrict__ X,
                                              int* __restrict__ count,
                                              int* __restrict__ rank,
                                              short* __restrict__ WbT,
                                              short* __restrict__ Xb,
                                              int* __restrict__ gstart,
                                              int NBc, int E, int N) {
    int b = blockIdx.x;
    if (b < NBc) {
        int e = b * 256 + threadIdx.x;
        int ET = E + N;
        if (e >= ET) return;
        int d = (e < E) ? ei[E + e] : (e - E);
        rank[e] = atomicAdd(&count[d], 1);   // unique within-dst rank
    } else if (b < NBc + 384) {
        int n = b - NBc;
        int k = threadIdx.x;
        WbT[n * 256 + k] = (short)bfr(W[(size_t)k * HO + n]);
    } else if (b == NBc + 384) {
        int g = threadIdx.x;
        if (g > NGRAPH) return;
        int lo = 0, hi = N;
        while (lo < hi) { int mid = (lo + hi) >> 1; if (batch[mid] < g) lo = mid + 1; else hi = mid; }
        gstart[g] = lo;
    } else {
        size_t base = (size_t)(b - (NBc + 385)) * 2048 + threadIdx.x * 8;
        if (base + 8 <= (size_t)N * F_IN) {
            float4 q0 = *(const float4*)(X + base);
            float4 q1 = *(const float4*)(X + base + 4);
            bf8 pk;
            pk[0] = (short)bfr(q0.x); pk[1] = (short)bfr(q0.y);
            pk[2] = (short)bfr(q0.z); pk[3] = (short)bfr(q0.w);
            pk[4] = (short)bfr(q1.x); pk[5] = (short)bfr(q1.y);
            pk[6] = (short)bfr(q1.z); pk[7] = (short)bfr(q1.w);
            *(bf8*)(Xb + base) = pk;
        }
    }
}

// ---- K1: barrier-free MFMA GEMM (fragments direct from global) + att-dot +
// biased-int8 epilogue. A frags from Xb (bf16, pre-converted), B frags from
// L2-hot WbT. No K-loop LDS, no K-loop barriers, no bank conflicts. ----
__global__ __launch_bounds__(256, 2) void gemm_att(const short* __restrict__ Xb,
                                                   const short* __restrict__ WbT,
                                                   const float* __restrict__ att_src,
                                                   const float* __restrict__ att_dst,
                                                   unsigned char* __restrict__ hc,
                                                   float* __restrict__ ni,
                                                   float* __restrict__ aDstO, int N) {
    __shared__ float lsS[64][8];
    __shared__ float lsD[64][8];
    __shared__ float lsM[64][8];
    __shared__ float sclS[64][4];
    int t = threadIdx.x;
    int w = t >> 6, lane = t & 63;
    int quad = lane >> 4, l15 = lane & 15;
    int rbase = blockIdx.x * 64;

    f4 acc[4][6] = {};
    const short* ap[4];
#pragma unroll
    for (int at = 0; at < 4; at++) {
        int r = rbase + at * 16 + l15;
        r = (r < N) ? r : (N - 1);            // clamped rows never stored
        ap[at] = Xb + (size_t)r * F_IN + quad * 8;
    }
    const short* bp = WbT + (size_t)(w * 96 + l15) * F_IN + quad * 8;

#pragma unroll
    for (int k0 = 0; k0 < F_IN; k0 += 32) {
        bf8 ar[4], br[6];
#pragma unroll
        for (int at = 0; at < 4; at++)
            ar[at] = *(const bf8*)(ap[at] + k0);
#pragma unroll
        for (int nt = 0; nt < 6; nt++)
            br[nt] = *(const bf8*)(bp + nt * 16 * F_IN + k0);
#pragma unroll
        for (int at = 0; at < 4; at++)
#pragma unroll
            for (int nt = 0; nt < 6; nt++)
                acc[at][nt] = __builtin_amdgcn_mfma_f32_16x16x32_bf16(ar[at], br[nt], acc[at][nt], 0, 0, 0);
    }

    // ---- attention-dot epilogue ----
    // w=0: all head0 (split 6) | w=1: nt<2 head0, rest head1 (split 2)
    // w=2: nt<4 head1, rest head2 (split 4) | w=3: all head2 (split 0)
    const int splits[4] = {6, 2, 4, 0};
    int split = splits[w];
    float asv[6], adv[6];
#pragma unroll
    for (int nt = 0; nt < 6; nt++) {
        int c = w * 96 + nt * 16 + l15;
        asv[nt] = att_src[c];
        adv[nt] = att_dst[c];
    }
#pragma unroll
    for (int at = 0; at < 4; at++) {
#pragma unroll
        for (int r = 0; r < 4; r++) {
            float paS = 0.f, pbS = 0.f, paD = 0.f, pbD = 0.f;
#pragma unroll
            for (int nt = 0; nt < 6; nt++) {
                float v = acc[at][nt][r];
                if (nt < split) { paS += v * asv[nt]; paD += v * adv[nt]; }
                else            { pbS += v * asv[nt]; pbD += v * adv[nt]; }
            }
#pragma unroll
            for (int off = 1; off < 16; off <<= 1) {
                paS += __shfl_xor(paS, off); pbS += __shfl_xor(pbS, off);
                paD += __shfl_xor(paD, off); pbD += __shfl_xor(pbD, off);
            }
            if (l15 == 0) {
                int row = at * 16 + quad * 4 + r;
                lsS[row][w * 2 + 0] = paS; lsS[row][w * 2 + 1] = pbS;
                lsD[row][w * 2 + 0] = paD; lsD[row][w * 2 + 1] = pbD;
            }
        }
    }
    // ---- per-head abs-max (same split/reduce structure, fmax instead of +) ----
#pragma unroll
    for (int at = 0; at < 4; at++) {
#pragma unroll
        for (int r = 0; r < 4; r++) {
            float pa = 0.f, pb = 0.f;
#pragma unroll
            for (int nt = 0; nt < 6; nt++) {
                float v = fabsf(acc[at][nt][r]);
                if (nt < split) pa = fmaxf(pa, v); else pb = fmaxf(pb, v);
            }
#pragma unroll
            for (int off = 1; off < 16; off <<= 1) {
                pa = fmaxf(pa, __shfl_xor(pa, off));
                pb = fmaxf(pb, __shfl_xor(pb, off));
            }
            if (l15 == 0) {
                int row = at * 16 + quad * 4 + r;
                lsM[row][w * 2 + 0] = pa; lsM[row][w * 2 + 1] = pb;
            }
        }
    }
    __syncthreads();
    if (t < 64) {
        // per-head max over the two contributing waves (same combine as aSrc)
        float s0 = fmaxf(lsM[t][0], lsM[t][2]);
        float s1 = fmaxf(lsM[t][3], lsM[t][4]);
        float s2 = fmaxf(lsM[t][5], lsM[t][7]);
        sclS[t][0] = (s0 > 0.f) ? 127.f / s0 : 0.f;
        sclS[t][1] = (s1 > 0.f) ? 127.f / s1 : 0.f;
        sclS[t][2] = (s2 > 0.f) ? 127.f / s2 : 0.f;
        int node = rbase + t;
        if (node < N) {
            aDstO[node * 3 + 0] = lsD[t][0] + lsD[t][2];
            aDstO[node * 3 + 1] = lsD[t][3] + lsD[t][4];
            aDstO[node * 3 + 2] = lsD[t][5] + lsD[t][7];
            float4 nA, nB;
            nA.x = lsS[t][0] + lsS[t][2];
            nA.y = lsS[t][3] + lsS[t][4];
            nA.z = lsS[t][5] + lsS[t][7];
            nA.w = s0 / 127.f;            // pre-divided decode scale
            nB.x = s1 / 127.f;
            nB.y = s2 / 127.f;
            nB.z = 0.f; nB.w = 0.f;
            *(float4*)(ni + (size_t)node * 8) = nA;
            *(float4*)(ni + (size_t)node * 8 + 4) = nB;
        }
    }
    __syncthreads();
    // ---- biased int8 quantize + byte store: hc[node*384 + ch] = q+128 ----
#pragma unroll
    for (int at = 0; at < 4; at++) {
#pragma unroll
        for (int nt = 0; nt < 6; nt++) {
            int hd = (w * 96 + nt * 16) >> 7;   // head of this 16-ch tile
#pragma unroll
            for (int r = 0; r < 4; r++) {
                int row = at * 16 + quad * 4 + r;
                int node = rbase + row;
                float rq = sclS[row][hd];
                int qi = (int)rintf(acc[at][nt][r] * rq) + 128;
                if (node < N) hc[(size_t)node * 384 + w * 96 + nt * 16 + l15] = (unsigned char)qi;
            }
        }
    }
}

// ---- K2a/b/c: hierarchical exclusive scan ----
__global__ __launch_bounds__(256) void scan_a(const int* __restrict__ count,
                                              int* __restrict__ offsets,
                                              int* __restrict__ bsums, int N) {
    __shared__ int tmp[256];
    int t = threadIdx.x;
    int i = blockIdx.x * 256 + t;
    int v = (i < N) ? count[i] : 0;
    tmp[t] = v;
    __syncthreads();
    for (int off = 1; off < 256; off <<= 1) {
        int x = (t >= off) ? tmp[t - off] : 0;
        __syncthreads();
        tmp[t] += x;
        __syncthreads();
    }
    if (i < N) offsets[i] = tmp[t] - v;
    if (t == 255) bsums[blockIdx.x] = tmp[255];
}

__global__ __launch_bounds__(256) void scan_b(int* __restrict__ bsums, int NB) {
    __shared__ int tmp[256];
    int t = threadIdx.x;
    int v = (t < NB) ? bsums[t] : 0;
    tmp[t] = v;
    __syncthreads();
    for (int off = 1; off < 256; off <<= 1) {
        int x = (t >= off) ? tmp[t - off] : 0;
        __syncthreads();
        tmp[t] += x;
        __syncthreads();
    }
    if (t < NB) bsums[t] = tmp[t] - v;
}

__global__ __launch_bounds__(256) void scan_c(int* __restrict__ offsets,
                                              const int* __restrict__ bsums, int N) {
    int i = blockIdx.x * 256 + threadIdx.x;
    if (i < N) offsets[i] += bsums[blockIdx.x];
}

// ---- K3: scatter src index into CSR — plain write via precomputed rank ----
__global__ __launch_bounds__(256) void scatter_k(const int* __restrict__ ei,
                                                 const int* __restrict__ rank,
                                                 const int* __restrict__ offsets,
                                                 int* __restrict__ csr_src, int E, int N) {
    int e = blockIdx.x * 256 + threadIdx.x;
    int ET = E + N;
    if (e >= ET) return;
    int s, d;
    if (e < E) { s = ei[e]; d = ei[E + e]; } else { s = e - E; d = s; }
    csr_src[offsets[d] + rank[e]] = s;
}

// ---- K4: fused softmax + biased-int8 gather aggregation, one wave per dst ----
// Weights/indices staged in LDS once per wave; perm+fma_mix decode; offset
// 1152*wsum subtracted once in the epilogue.
__global__ __launch_bounds__(256) void aggregate_k(const unsigned* __restrict__ hcw,
                                                   const int* __restrict__ csr_src,
                                                   const int* __restrict__ offsets,
                                                   const int* __restrict__ count,
                                                   const float* __restrict__ ni,
                                                   const float* __restrict__ a_dst,
                                                   const float* __restrict__ bias,
                                                   unsigned* __restrict__ outb, int N) {
    __shared__ float ws[4][3][68];   // [wave][head][edge], 68-pad: heads hit distinct banks
    __shared__ int   si[4][64];      // [wave][edge] src index
    int wv = threadIdx.x >> 6;
    int wid = blockIdx.x * 4 + wv;
    int lane = threadIdx.x & 63;
    if (wid >= N) return;
    int start = offsets[wid], n = count[wid];
    float ad0 = a_dst[wid * 3 + 0], ad1 = a_dst[wid * 3 + 1], ad2 = a_dst[wid * 3 + 2];
    int hm = (lane < 48) ? (lane >> 4) : 0;   // head of this lane's 8 channels
    int off = (lane < 48) ? 2 * lane : 0;     // dword offset into 96-dword row
    float acc[8] = {0.f, 0.f, 0.f, 0.f, 0.f, 0.f, 0.f, 0.f};
    float wsum = 0.f;
    float i0, i1, i2;
    const unsigned c64 = 0x64646464u;

    if (n <= 64) {
        int sreg = 0;
        float l0 = -INFINITY, l1 = -INFINITY, l2 = -INFINITY;
        float s0v = 0.f, s1v = 0.f, s2v = 0.f;
        if (lane < n) {
            sreg = csr_src[start + lane];
            float4 A = *(const float4*)(ni + (size_t)sreg * 8);
            float4 B = *(const float4*)(ni + (size_t)sreg * 8 + 4);
            l0 = lrelu(A.x + ad0); l1 = lrelu(A.y + ad1); l2 = lrelu(A.z + ad2);
            s0v = A.w; s1v = B.x; s2v = B.y;
        }
        float m0 = l0, m1 = l1, m2 = l2;
#pragma unroll
        for (int o = 1; o < 64; o <<= 1) {
            m0 = fmaxf(m0, __shfl_xor(m0, o));
            m1 = fmaxf(m1, __shfl_xor(m1, o));
            m2 = fmaxf(m2, __shfl_xor(m2, o));
        }
        float e0 = (lane < n) ? expf(l0 - m0) : 0.f;
        float e1 = (lane < n) ? expf(l1 - m1) : 0.f;
        float e2 = (lane < n) ? expf(l2 - m2) : 0.f;
        float s0 = e0, s1 = e1, s2 = e2;
#pragma unroll
        for (int o = 1; o < 64; o <<= 1) {
            s0 += __shfl_xor(s0, o);
            s1 += __shfl_xor(s1, o);
            s2 += __shfl_xor(s2, o);
        }
        i0 = 1.f / (s0 + 1e-16f); i1 = 1.f / (s1 + 1e-16f); i2 = 1.f / (s2 + 1e-16f);
        // scale-folded unnormalized weights; 0 for idle lanes
        ws[wv][0][lane] = e0 * s0v;
        ws[wv][1][lane] = e1 * s1v;
        ws[wv][2][lane] = e2 * s2v;
        si[wv][lane] = sreg;
        __builtin_amdgcn_wave_barrier();   // order LDS writes before reads (in-wave)

        for (int j = 0; j < n; j += 8) {
            int4 ia = *(const int4*)&si[wv][j];        // broadcast reads
            int4 ib = *(const int4*)&si[wv][j + 4];
            u2v u0 = *(const u2v*)(hcw + (size_t)ia.x * 96 + off);
            u2v u1 = *(const u2v*)(hcw + (size_t)ia.y * 96 + off);
            u2v u2 = *(const u2v*)(hcw + (size_t)ia.z * 96 + off);
            u2v u3 = *(const u2v*)(hcw + (size_t)ia.w * 96 + off);
            u2v u4 = *(const u2v*)(hcw + (size_t)ib.x * 96 + off);
            u2v u5 = *(const u2v*)(hcw + (size_t)ib.y * 96 + off);
            u2v u6 = *(const u2v*)(hcw + (size_t)ib.z * 96 + off);
            u2v u7 = *(const u2v*)(hcw + (size_t)ib.w * 96 + off);
            float4 wa = *(const float4*)&ws[wv][hm][j];
            float4 wb = *(const float4*)&ws[wv][hm][j + 4];
            wsum += (wa.x + wa.y + wa.z + wa.w) + (wb.x + wb.y + wb.z + wb.w);
            dec8_mix(acc, wa.x, u0.x, u0.y, c64);
            dec8_mix(acc, wa.y, u1.x, u1.y, c64);
            dec8_mix(acc, wa.z, u2.x, u2.y, c64);
            dec8_mix(acc, wa.w, u3.x, u3.y, c64);
            dec8_mix(acc, wb.x, u4.x, u4.y, c64);
            dec8_mix(acc, wb.y, u5.x, u5.y, c64);
            dec8_mix(acc, wb.z, u6.x, u6.y, c64);
            dec8_mix(acc, wb.w, u7.x, u7.y, c64);
        }
    } else {
        float m0 = -INFINITY, m1 = -INFINITY, m2 = -INFINITY;
        for (int j = lane; j < n; j += 64) {
            int s = csr_src[start + j];
            float4 A = *(const float4*)(ni + (size_t)s * 8);
            m0 = fmaxf(m0, lrelu(A.x + ad0));
            m1 = fmaxf(m1, lrelu(A.y + ad1));
            m2 = fmaxf(m2, lrelu(A.z + ad2));
        }
#pragma unroll
        for (int o = 1; o < 64; o <<= 1) {
            m0 = fmaxf(m0, __shfl_xor(m0, o));
            m1 = fmaxf(m1, __shfl_xor(m1, o));
            m2 = fmaxf(m2, __shfl_xor(m2, o));
        }
        float s0 = 0.f, s1 = 0.f, s2 = 0.f;
        for (int j = lane; j < n; j += 64) {
            int s = csr_src[start + j];
            float4 A = *(const float4*)(ni + (size_t)s * 8);
            s0 += expf(lrelu(A.x + ad0) - m0);
            s1 += expf(lrelu(A.y + ad1) - m1);
            s2 += expf(lrelu(A.z + ad2) - m2);
        }
#pragma unroll
        for (int o = 1; o < 64; o <<= 1) {
            s0 += __shfl_xor(s0, o);
            s1 += __shfl_xor(s1, o);
            s2 += __shfl_xor(s2, o);
        }
        i0 = 1.f / (s0 + 1e-16f); i1 = 1.f / (s1 + 1e-16f); i2 = 1.f / (s2 + 1e-16f);
        for (int j = 0; j < n; j++) {
            int s = csr_src[start + j];
            float4 A = *(const float4*)(ni + (size_t)s * 8);
            float4 B = *(const float4*)(ni + (size_t)s * 8 + 4);
            float w0 = expf(lrelu(A.x + ad0) - m0) * A.w;
            float w1 = expf(lrelu(A.y + ad1) - m1) * B.x;
            float w2 = expf(lrelu(A.z + ad2) - m2) * B.y;
            float wm = (hm == 0) ? w0 : ((hm == 1) ? w1 : w2);
            u2v u = *(const u2v*)(hcw + (size_t)s * 96 + off);
            wsum += wm;
            dec8_mix(acc, wm, u.x, u.y, c64);
        }
    }

    if (lane < 48) {
        float im = (hm == 0) ? i0 : ((hm == 1) ? i1 : i2);
        float corr = 1152.f * wsum;          // remove (1024+128) bias per unit weight
        float4 b0 = *(const float4*)(bias + 8 * lane);
        float4 b1 = *(const float4*)(bias + 8 * lane + 4);
        float bb[8] = {b0.x, b0.y, b0.z, b0.w, b1.x, b1.y, b1.z, b1.w};
        u4v pk;
#pragma unroll
        for (int j = 0; j < 4; j++) {
            float x0 = (acc[2 * j] - corr) * im + bb[2 * j];
            float x1 = (acc[2 * j + 1] - corr) * im + bb[2 * j + 1];
            x0 = (x0 > 0.f) ? x0 : 0.f;
            x1 = (x1 > 0.f) ? x1 : 0.f;
            pk[j] = (unsigned)bfr(x0) | ((unsigned)bfr(x1) << 16);
        }
        *(u4v*)(outb + (size_t)wid * 192 + 4 * lane) = pk;
    }
}

// ---- K5: segment-sum pool over contiguous per-graph row ranges ----
__global__ __launch_bounds__(192) void pool_k(const unsigned* __restrict__ outb,
                                              const int* __restrict__ gstart,
                                              float* __restrict__ pooled) {
    int g = blockIdx.x;
    int chunk = blockIdx.y;
    int t = threadIdx.x;
    int lo = gstart[g], hi = gstart[g + 1];
    float al = 0.f, ah = 0.f;
    for (int r = lo + chunk; r < hi; r += 8) {
        unsigned u = outb[(size_t)r * 192 + t];
        al += bflo(u);
        ah += bfhi(u);
    }
    atomicAdd(&pooled[g * HO + 2 * t], al);
    atomicAdd(&pooled[g * HO + 2 * t + 1], ah);
}

// ---- K6: FC over pooled means ----
__global__ __launch_bounds__(64) void fc_k(const float* __restrict__ pooled,
                                           const int* __restrict__ gstart,
                                           const float* __restrict__ fc_w,
                                           const float* __restrict__ fc_b,
                                           float* __restrict__ out) {
    int g = blockIdx.x;
    int lane = threadIdx.x;
    float a0 = 0.f, a1 = 0.f;
#pragma unroll
    for (int k = 0; k < 6; k++) {
        int c = lane + 64 * k;
        float pv = pooled[g * HO + c];
        a0 += pv * fc_w[c * 2 + 0];
        a1 += pv * fc_w[c * 2 + 1];
    }
#pragma unroll
    for (int off = 32; off > 0; off >>= 1) {
        a0 += __shfl_down(a0, off);
        a1 += __shfl_down(a1, off);
    }
    if (lane == 0) {
        float cnt = fmaxf((float)(gstart[g + 1] - gstart[g]), 1.0f);
        out[g * 2 + 0] = a0 / cnt + fc_b[0];
        out[g * 2 + 1] = a1 / cnt + fc_b[1];
    }
}

extern "C" void kernel_launch(void* const* d_in, const int* in_sizes, int n_in,
                              void* d_out, int out_size, void* d_ws, size_t ws_size,
                              hipStream_t stream) {
    const float* x       = (const float*)d_in[0];
    const int*   ei      = (const int*)d_in[1];
    const int*   batch   = (const int*)d_in[2];
    const float* W       = (const float*)d_in[3];
    const float* att_src = (const float*)d_in[4];
    const float* att_dst = (const float*)d_in[5];
    const float* bias    = (const float*)d_in[6];
    const float* fc_w    = (const float*)d_in[7];
    const float* fc_b    = (const float*)d_in[8];
    float* out = (float*)d_out;

    const int N = in_sizes[2];
    const int E = in_sizes[1] / 2;
    const int ET = E + N;

    char* p = (char*)d_ws;
    auto alloc = [&](size_t bytes) -> char* {
        char* r = p;
        p += (bytes + 255) & ~(size_t)255;
        return r;
    };
    short*         wbt    = (short*)alloc((size_t)HO * F_IN * 2);
    short*         xb     = (short*)alloc((size_t)N * F_IN * 2);
    unsigned char* hc     = (unsigned char*)alloc((size_t)N * 384);
    unsigned*      outb   = (unsigned*)alloc((size_t)N * 192 * 4);
    float*         ni     = (float*)alloc((size_t)N * 8 * 4);
    float*         a_dst  = (float*)alloc((size_t)N * 3 * 4);
    char*          zstart = p;
    int*           count  = (int*)alloc((size_t)N * 4);              // zeroed
    float*         pooled = (float*)alloc((size_t)NGRAPH * HO * 4);  // zeroed
    size_t         zbytes = (size_t)(p - zstart);
    int*           offsets = (int*)alloc((size_t)N * 4);
    int*           rank    = (int*)alloc((size_t)ET * 4);
    int*           bsums   = (int*)alloc(4096);
    int*           gstart  = (int*)alloc(1024);
    int*           csr_src = (int*)alloc((size_t)ET * 4);

    hipMemsetAsync(zstart, 0, zbytes, stream);

    int NBc = (ET + 255) / 256;
    int NXc = (int)(((size_t)N * F_IN + 2047) / 2048);
    misc_k<<<NBc + 384 + 1 + NXc, 256, 0, stream>>>(ei, W, batch, x, count, rank,
                                                    wbt, xb, gstart, NBc, E, N);
    gemm_att<<<(N + 63) / 64, 256, 0, stream>>>(xb, wbt, att_src, att_dst,
                                                hc, ni, a_dst, N);
    int NB = (N + 255) / 256;
    scan_a<<<NB, 256, 0, stream>>>(count, offsets, bsums, N);
    scan_b<<<1, 256, 0, stream>>>(bsums, NB);
    scan_c<<<NB, 256, 0, stream>>>(offsets, bsums, N);
    scatter_k<<<(ET + 255) / 256, 256, 0, stream>>>(ei, rank, offsets, csr_src, E, N);
    aggregate_k<<<(N + 3) / 4, 256, 0, stream>>>((const unsigned*)hc, csr_src, offsets,
                                                 count, ni, a_dst, bias, outb, N);
    dim3 pg(NGRAPH, 8);
    pool_k<<<pg, 192, 0, stream>>>(outb, gstart, pooled);
    fc_k<<<NGRAPH, 64, 0, stream>>>(pooled, gstart, fc_w, fc_b, out);

    (void)n_in; (void)out_size; (void)ws_size;
}

// Round 6
// 308.306 us; speedup vs baseline: 1.0025x; 1.0025x over previous
//
#include <hip/hip_runtime.h>
#include <hip/hip_bf16.h>
#include <math.h>

#define HEADS 3
#define HO 384
#define NGRAPH 64
#define F_IN 256
#define SLOPE 0.2f

typedef __attribute__((ext_vector_type(8))) short bf8;
typedef __attribute__((ext_vector_type(4))) float f4;
typedef __attribute__((ext_vector_type(2))) unsigned u2v;
typedef __attribute__((ext_vector_type(4))) unsigned u4v;

// ---- bf16 helpers ----
__device__ __forceinline__ unsigned short bfr(float f) {
    unsigned u = __float_as_uint(f);
    u += 0x7fffu + ((u >> 16) & 1u);
    return (unsigned short)(u >> 16);
}
__device__ __forceinline__ float bflo(unsigned u) { return __uint_as_float(u << 16); }
__device__ __forceinline__ float bfhi(unsigned u) { return __uint_as_float(u & 0xffff0000u); }
__device__ __forceinline__ float lrelu(float v) { return (v > 0.f) ? v : SLOPE * v; }

// ---- biased-byte decode: bytes store q+128; v_perm builds half2(1024+b) (exact
// in f16), v_fma_mix_f32 accumulates wm*(1152+q) into f32 acc. ----
__device__ __forceinline__ void mix2(float& a0, float& a1, unsigned h2, float wm) {
    asm("v_fma_mix_f32 %0, %2, %3, %0 op_sel:[0,0,0] op_sel_hi:[1,0,0]\n\t"
        "v_fma_mix_f32 %1, %2, %3, %1 op_sel:[1,0,0] op_sel_hi:[1,0,0]"
        : "+v"(a0), "+v"(a1)
        : "v"(h2), "v"(wm));
}
__device__ __forceinline__ void dec8_mix(float* acc, float wm, unsigned ux, unsigned uy,
                                         unsigned c64) {
    unsigned p0 = __builtin_amdgcn_perm(ux, c64, 0x00050004u); // [b0,0x64,b1,0x64]
    unsigned p1 = __builtin_amdgcn_perm(ux, c64, 0x00070006u);
    unsigned p2 = __builtin_amdgcn_perm(uy, c64, 0x00050004u);
    unsigned p3 = __builtin_amdgcn_perm(uy, c64, 0x00070006u);
    mix2(acc[0], acc[1], p0, wm);
    mix2(acc[2], acc[3], p1, wm);
    mix2(acc[4], acc[5], p2, wm);
    mix2(acc[6], acc[7], p3, wm);
}

// ---- K0: fused misc pre-pass (block-range dispatch):
//   [0, NBc)              : degree count + per-edge rank
//   [NBc, NBc+384)        : W -> WbT bf16 transpose-convert
//   NBc+384               : per-graph start offsets
//   NBc+385               : WaT = folded attention weights (16 x 256 bf16):
//                           rows 0-2 = Wsrc[:,h], rows 3-5 = Wdst[:,h], 6-15 = 0
//   [NBc+386, +NXc)       : X f32 -> Xb bf16 streaming convert (2048 elems/blk)
__global__ __launch_bounds__(256) void misc_k(const int* __restrict__ ei,
                                              const float* __restrict__ W,
                                              const int* __restrict__ batch,
                                              const float* __restrict__ X,
                                              const float* __restrict__ att_src,
                                              const float* __restrict__ att_dst,
                                              int* __restrict__ count,
                                              int* __restrict__ rank,
                                              short* __restrict__ WbT,
                                              short* __restrict__ WaT,
                                              short* __restrict__ Xb,
                                              int* __restrict__ gstart,
                                              int NBc, int E, int N) {
    int b = blockIdx.x;
    if (b < NBc) {
        int e = b * 256 + threadIdx.x;
        int ET = E + N;
        if (e >= ET) return;
        int d = (e < E) ? ei[E + e] : (e - E);
        rank[e] = atomicAdd(&count[d], 1);   // unique within-dst rank
    } else if (b < NBc + 384) {
        int n = b - NBc;
        int k = threadIdx.x;
        WbT[n * 256 + k] = (short)bfr(W[(size_t)k * HO + n]);
    } else if (b == NBc + 384) {
        int g = threadIdx.x;
        if (g > NGRAPH) return;
        int lo = 0, hi = N;
        while (lo < hi) { int mid = (lo + hi) >> 1; if (batch[mid] < g) lo = mid + 1; else hi = mid; }
        gstart[g] = lo;
    } else if (b == NBc + 385) {
        // a_src/a_dst are linear in X: fold att dot into 3+3 GEMM columns.
        int k = threadIdx.x;   // 0..255 (F_IN)
        float s[6] = {0.f, 0.f, 0.f, 0.f, 0.f, 0.f};
        const float* wr = W + (size_t)k * HO;
        for (int h = 0; h < 3; h++) {
            float a0 = 0.f, a1 = 0.f;
            for (int c = 0; c < 128; c++) {
                float wv = wr[h * 128 + c];
                a0 += wv * att_src[h * 128 + c];
                a1 += wv * att_dst[h * 128 + c];
            }
            s[h] = a0; s[3 + h] = a1;
        }
        for (int c = 0; c < 6; c++)  WaT[c * 256 + k] = (short)bfr(s[c]);
        for (int c = 6; c < 16; c++) WaT[c * 256 + k] = 0;
    } else {
        size_t base = (size_t)(b - (NBc + 386)) * 2048 + threadIdx.x * 8;
        if (base + 8 <= (size_t)N * F_IN) {
            float4 q0 = *(const float4*)(X + base);
            float4 q1 = *(const float4*)(X + base + 4);
            bf8 pk;
            pk[0] = (short)bfr(q0.x); pk[1] = (short)bfr(q0.y);
            pk[2] = (short)bfr(q0.z); pk[3] = (short)bfr(q0.w);
            pk[4] = (short)bfr(q1.x); pk[5] = (short)bfr(q1.y);
            pk[6] = (short)bfr(q1.z); pk[7] = (short)bfr(q1.w);
            *(bf8*)(Xb + base) = pk;
        }
    }
}

// ---- K1: 32-row/block MFMA GEMM (2x grid, 4 blocks/CU) + folded att columns
// + biased-int8 epilogue. Wave w owns cols [w*96, w*96+96); wave 3 additionally
// computes the 16-col WaT tile whose cols 0-5 are a_src/a_dst. ----
__global__ __launch_bounds__(256, 4) void gemm_att(const short* __restrict__ Xb,
                                                   const short* __restrict__ WbT,
                                                   const short* __restrict__ WaT,
                                                   unsigned char* __restrict__ hc,
                                                   float* __restrict__ ni,
                                                   float* __restrict__ aDstO, int N) {
    __shared__ float lsM[32][8];
    __shared__ float lsA[32][6];
    __shared__ float sclS[32][4];
    int t = threadIdx.x;
    int w = t >> 6, lane = t & 63;
    int quad = lane >> 4, l15 = lane & 15;
    int rbase = blockIdx.x * 32;

    f4 acc[2][6] = {};
    f4 acca[2] = {};
    const short* ap[2];
#pragma unroll
    for (int at = 0; at < 2; at++) {
        int r = rbase + at * 16 + l15;
        r = (r < N) ? r : (N - 1);            // clamped rows never stored
        ap[at] = Xb + (size_t)r * F_IN + quad * 8;
    }
    const short* bp = WbT + (size_t)(w * 96 + l15) * F_IN + quad * 8;
    const short* bpa = WaT + (size_t)l15 * F_IN + quad * 8;

#pragma unroll
    for (int k0 = 0; k0 < F_IN; k0 += 32) {
        bf8 ar[2], br[6];
#pragma unroll
        for (int at = 0; at < 2; at++)
            ar[at] = *(const bf8*)(ap[at] + k0);
#pragma unroll
        for (int nt = 0; nt < 6; nt++)
            br[nt] = *(const bf8*)(bp + nt * 16 * F_IN + k0);
#pragma unroll
        for (int at = 0; at < 2; at++)
#pragma unroll
            for (int nt = 0; nt < 6; nt++)
                acc[at][nt] = __builtin_amdgcn_mfma_f32_16x16x32_bf16(ar[at], br[nt], acc[at][nt], 0, 0, 0);
        if (w == 3) {
            bf8 ba = *(const bf8*)(bpa + k0);
            acca[0] = __builtin_amdgcn_mfma_f32_16x16x32_bf16(ar[0], ba, acca[0], 0, 0, 0);
            acca[1] = __builtin_amdgcn_mfma_f32_16x16x32_bf16(ar[1], ba, acca[1], 0, 0, 0);
        }
    }

    // ---- per-head abs-max. Head boundaries at cols 128/256:
    // w0: all head0 | w1: nt<2 head0, rest head1 | w2: nt<4 head1, rest head2
    // | w3: all head2. splits={6,2,4,6}; combine below uses slots {0,2},{3,4},{5,6}.
    const int splits[4] = {6, 2, 4, 6};
    int split = splits[w];
#pragma unroll
    for (int at = 0; at < 2; at++) {
#pragma unroll
        for (int r = 0; r < 4; r++) {
            float pa = 0.f, pb = 0.f;
#pragma unroll
            for (int nt = 0; nt < 6; nt++) {
                float v = fabsf(acc[at][nt][r]);
                if (nt < split) pa = fmaxf(pa, v); else pb = fmaxf(pb, v);
            }
#pragma unroll
            for (int off = 1; off < 16; off <<= 1) {
                pa = fmaxf(pa, __shfl_xor(pa, off));
                pb = fmaxf(pb, __shfl_xor(pb, off));
            }
            if (l15 == 0) {
                int row = at * 16 + quad * 4 + r;
                lsM[row][w * 2 + 0] = pa; lsM[row][w * 2 + 1] = pb;
            }
        }
    }
    // ---- a_src/a_dst from the WaT tile (C-layout: col=l15, row=quad*4+reg) ----
    if (w == 3) {
#pragma unroll
        for (int at = 0; at < 2; at++)
#pragma unroll
            for (int r = 0; r < 4; r++)
                if (l15 < 6) lsA[at * 16 + quad * 4 + r][l15] = acca[at][r];
    }
    __syncthreads();
    if (t < 32) {
        float s0 = fmaxf(lsM[t][0], lsM[t][2]);
        float s1 = fmaxf(lsM[t][3], lsM[t][4]);
        float s2 = fmaxf(lsM[t][5], lsM[t][6]);
        sclS[t][0] = (s0 > 0.f) ? 127.f / s0 : 0.f;
        sclS[t][1] = (s1 > 0.f) ? 127.f / s1 : 0.f;
        sclS[t][2] = (s2 > 0.f) ? 127.f / s2 : 0.f;
        int node = rbase + t;
        if (node < N) {
            aDstO[node * 3 + 0] = lsA[t][3];
            aDstO[node * 3 + 1] = lsA[t][4];
            aDstO[node * 3 + 2] = lsA[t][5];
            float4 nA, nB;
            nA.x = lsA[t][0];
            nA.y = lsA[t][1];
            nA.z = lsA[t][2];
            nA.w = s0 / 127.f;            // pre-divided decode scale
            nB.x = s1 / 127.f;
            nB.y = s2 / 127.f;
            nB.z = 0.f; nB.w = 0.f;
            *(float4*)(ni + (size_t)node * 8) = nA;
            *(float4*)(ni + (size_t)node * 8 + 4) = nB;
        }
    }
    __syncthreads();
    // ---- biased int8 quantize + byte store: hc[node*384 + ch] = q+128 ----
#pragma unroll
    for (int at = 0; at < 2; at++) {
#pragma unroll
        for (int nt = 0; nt < 6; nt++) {
            int hd = (w * 96 + nt * 16) >> 7;   // head of this 16-ch tile
#pragma unroll
            for (int r = 0; r < 4; r++) {
                int row = at * 16 + quad * 4 + r;
                int node = rbase + row;
                float rq = sclS[row][hd];
                int qi = (int)rintf(acc[at][nt][r] * rq) + 128;
                if (node < N) hc[(size_t)node * 384 + w * 96 + nt * 16 + l15] = (unsigned char)qi;
            }
        }
    }
}

// ---- K2a/b/c: hierarchical exclusive scan ----
__global__ __launch_bounds__(256) void scan_a(const int* __restrict__ count,
                                              int* __restrict__ offsets,
                                              int* __restrict__ bsums, int N) {
    __shared__ int tmp[256];
    int t = threadIdx.x;
    int i = blockIdx.x * 256 + t;
    int v = (i < N) ? count[i] : 0;
    tmp[t] = v;
    __syncthreads();
    for (int off = 1; off < 256; off <<= 1) {
        int x = (t >= off) ? tmp[t - off] : 0;
        __syncthreads();
        tmp[t] += x;
        __syncthreads();
    }
    if (i < N) offsets[i] = tmp[t] - v;
    if (t == 255) bsums[blockIdx.x] = tmp[255];
}

__global__ __launch_bounds__(256) void scan_b(int* __restrict__ bsums, int NB) {
    __shared__ int tmp[256];
    int t = threadIdx.x;
    int v = (t < NB) ? bsums[t] : 0;
    tmp[t] = v;
    __syncthreads();
    for (int off = 1; off < 256; off <<= 1) {
        int x = (t >= off) ? tmp[t - off] : 0;
        __syncthreads();
        tmp[t] += x;
        __syncthreads();
    }
    if (t < NB) bsums[t] = tmp[t] - v;
}

__global__ __launch_bounds__(256) void scan_c(int* __restrict__ offsets,
                                              const int* __restrict__ bsums, int N) {
    int i = blockIdx.x * 256 + threadIdx.x;
    if (i < N) offsets[i] += bsums[blockIdx.x];
}

// ---- K3: scatter src index into CSR — plain write via precomputed rank ----
__global__ __launch_bounds__(256) void scatter_k(const int* __restrict__ ei,
                                                 const int* __restrict__ rank,
                                                 const int* __restrict__ offsets,
                                                 int* __restrict__ csr_src, int E, int N) {
    int e = blockIdx.x * 256 + threadIdx.x;
    int ET = E + N;
    if (e >= ET) return;
    int s, d;
    if (e < E) { s = ei[e]; d = ei[E + e]; } else { s = e - E; d = s; }
    csr_src[offsets[d] + rank[e]] = s;
}

// ---- K4: fused softmax + biased-int8 gather aggregation, one wave per dst ----
__global__ __launch_bounds__(256) void aggregate_k(const unsigned* __restrict__ hcw,
                                                   const int* __restrict__ csr_src,
                                                   const int* __restrict__ offsets,
                                                   const int* __restrict__ count,
                                                   const float* __restrict__ ni,
                                                   const float* __restrict__ a_dst,
                                                   const float* __restrict__ bias,
                                                   unsigned* __restrict__ outb, int N) {
    __shared__ float ws[4][3][68];   // [wave][head][edge], 68-pad: heads hit distinct banks
    __shared__ int   si[4][64];      // [wave][edge] src index
    int wv = threadIdx.x >> 6;
    int wid = blockIdx.x * 4 + wv;
    int lane = threadIdx.x & 63;
    if (wid >= N) return;
    int start = offsets[wid], n = count[wid];
    float ad0 = a_dst[wid * 3 + 0], ad1 = a_dst[wid * 3 + 1], ad2 = a_dst[wid * 3 + 2];
    int hm = (lane < 48) ? (lane >> 4) : 0;   // head of this lane's 8 channels
    int off = (lane < 48) ? 2 * lane : 0;     // dword offset into 96-dword row
    float acc[8] = {0.f, 0.f, 0.f, 0.f, 0.f, 0.f, 0.f, 0.f};
    float wsum = 0.f;
    float i0, i1, i2;
    const unsigned c64 = 0x64646464u;

    if (n <= 64) {
        int sreg = 0;
        float l0 = -INFINITY, l1 = -INFINITY, l2 = -INFINITY;
        float s0v = 0.f, s1v = 0.f, s2v = 0.f;
        if (lane < n) {
            sreg = csr_src[start + lane];
            float4 A = *(const float4*)(ni + (size_t)sreg * 8);
            float4 B = *(const float4*)(ni + (size_t)sreg * 8 + 4);
            l0 = lrelu(A.x + ad0); l1 = lrelu(A.y + ad1); l2 = lrelu(A.z + ad2);
            s0v = A.w; s1v = B.x; s2v = B.y;
        }
        float m0 = l0, m1 = l1, m2 = l2;
#pragma unroll
        for (int o = 1; o < 64; o <<= 1) {
            m0 = fmaxf(m0, __shfl_xor(m0, o));
            m1 = fmaxf(m1, __shfl_xor(m1, o));
            m2 = fmaxf(m2, __shfl_xor(m2, o));
        }
        float e0 = (lane < n) ? expf(l0 - m0) : 0.f;
        float e1 = (lane < n) ? expf(l1 - m1) : 0.f;
        float e2 = (lane < n) ? expf(l2 - m2) : 0.f;
        float s0 = e0, s1 = e1, s2 = e2;
#pragma unroll
        for (int o = 1; o < 64; o <<= 1) {
            s0 += __shfl_xor(s0, o);
            s1 += __shfl_xor(s1, o);
            s2 += __shfl_xor(s2, o);
        }
        i0 = 1.f / (s0 + 1e-16f); i1 = 1.f / (s1 + 1e-16f); i2 = 1.f / (s2 + 1e-16f);
        // scale-folded unnormalized weights; 0 for idle lanes
        ws[wv][0][lane] = e0 * s0v;
        ws[wv][1][lane] = e1 * s1v;
        ws[wv][2][lane] = e2 * s2v;
        si[wv][lane] = sreg;
        __builtin_amdgcn_wave_barrier();   // order LDS writes before reads (in-wave)

        for (int j = 0; j < n; j += 8) {
            int4 ia = *(const int4*)&si[wv][j];        // broadcast reads
            int4 ib = *(const int4*)&si[wv][j + 4];
            u2v u0 = *(const u2v*)(hcw + (size_t)ia.x * 96 + off);
            u2v u1 = *(const u2v*)(hcw + (size_t)ia.y * 96 + off);
            u2v u2 = *(const u2v*)(hcw + (size_t)ia.z * 96 + off);
            u2v u3 = *(const u2v*)(hcw + (size_t)ia.w * 96 + off);
            u2v u4 = *(const u2v*)(hcw + (size_t)ib.x * 96 + off);
            u2v u5 = *(const u2v*)(hcw + (size_t)ib.y * 96 + off);
            u2v u6 = *(const u2v*)(hcw + (size_t)ib.z * 96 + off);
            u2v u7 = *(const u2v*)(hcw + (size_t)ib.w * 96 + off);
            float4 wa = *(const float4*)&ws[wv][hm][j];
            float4 wb = *(const float4*)&ws[wv][hm][j + 4];
            wsum += (wa.x + wa.y + wa.z + wa.w) + (wb.x + wb.y + wb.z + wb.w);
            dec8_mix(acc, wa.x, u0.x, u0.y, c64);
            dec8_mix(acc, wa.y, u1.x, u1.y, c64);
            dec8_mix(acc, wa.z, u2.x, u2.y, c64);
            dec8_mix(acc, wa.w, u3.x, u3.y, c64);
            dec8_mix(acc, wb.x, u4.x, u4.y, c64);
            dec8_mix(acc, wb.y, u5.x, u5.y, c64);
            dec8_mix(acc, wb.z, u6.x, u6.y, c64);
            dec8_mix(acc, wb.w, u7.x, u7.y, c64);
        }
    } else {
        float m0 = -INFINITY, m1 = -INFINITY, m2 = -INFINITY;
        for (int j = lane; j < n; j += 64) {
            int s = csr_src[start + j];
            float4 A = *(const float4*)(ni + (size_t)s * 8);
            m0 = fmaxf(m0, lrelu(A.x + ad0));
            m1 = fmaxf(m1, lrelu(A.y + ad1));
            m2 = fmaxf(m2, lrelu(A.z + ad2));
        }
#pragma unroll
        for (int o = 1; o < 64; o <<= 1) {
            m0 = fmaxf(m0, __shfl_xor(m0, o));
            m1 = fmaxf(m1, __shfl_xor(m1, o));
            m2 = fmaxf(m2, __shfl_xor(m2, o));
        }
        float s0 = 0.f, s1 = 0.f, s2 = 0.f;
        for (int j = lane; j < n; j += 64) {
            int s = csr_src[start + j];
            float4 A = *(const float4*)(ni + (size_t)s * 8);
            s0 += expf(lrelu(A.x + ad0) - m0);
            s1 += expf(lrelu(A.y + ad1) - m1);
            s2 += expf(lrelu(A.z + ad2) - m2);
        }
#pragma unroll
        for (int o = 1; o < 64; o <<= 1) {
            s0 += __shfl_xor(s0, o);
            s1 += __shfl_xor(s1, o);
            s2 += __shfl_xor(s2, o);
        }
        i0 = 1.f / (s0 + 1e-16f); i1 = 1.f / (s1 + 1e-16f); i2 = 1.f / (s2 + 1e-16f);
        for (int j = 0; j < n; j++) {
            int s = csr_src[start + j];
            float4 A = *(const float4*)(ni + (size_t)s * 8);
            float4 B = *(const float4*)(ni + (size_t)s * 8 + 4);
            float w0 = expf(lrelu(A.x + ad0) - m0) * A.w;
            float w1 = expf(lrelu(A.y + ad1) - m1) * B.x;
            float w2 = expf(lrelu(A.z + ad2) - m2) * B.y;
            float wm = (hm == 0) ? w0 : ((hm == 1) ? w1 : w2);
            u2v u = *(const u2v*)(hcw + (size_t)s * 96 + off);
            wsum += wm;
            dec8_mix(acc, wm, u.x, u.y, c64);
        }
    }

    if (lane < 48) {
        float im = (hm == 0) ? i0 : ((hm == 1) ? i1 : i2);
        float corr = 1152.f * wsum;          // remove (1024+128) bias per unit weight
        float4 b0 = *(const float4*)(bias + 8 * lane);
        float4 b1 = *(const float4*)(bias + 8 * lane + 4);
        float bb[8] = {b0.x, b0.y, b0.z, b0.w, b1.x, b1.y, b1.z, b1.w};
        u4v pk;
#pragma unroll
        for (int j = 0; j < 4; j++) {
            float x0 = (acc[2 * j] - corr) * im + bb[2 * j];
            float x1 = (acc[2 * j + 1] - corr) * im + bb[2 * j + 1];
            x0 = (x0 > 0.f) ? x0 : 0.f;
            x1 = (x1 > 0.f) ? x1 : 0.f;
            pk[j] = (unsigned)bfr(x0) | ((unsigned)bfr(x1) << 16);
        }
        *(u4v*)(outb + (size_t)wid * 192 + 4 * lane) = pk;
    }
}

// ---- K5: segment-sum pool over contiguous per-graph row ranges ----
__global__ __launch_bounds__(192) void pool_k(const unsigned* __restrict__ outb,
                                              const int* __restrict__ gstart,
                                              float* __restrict__ pooled) {
    int g = blockIdx.x;
    int chunk = blockIdx.y;
    int t = threadIdx.x;
    int lo = gstart[g], hi = gstart[g + 1];
    float al = 0.f, ah = 0.f;
    for (int r = lo + chunk; r < hi; r += 8) {
        unsigned u = outb[(size_t)r * 192 + t];
        al += bflo(u);
        ah += bfhi(u);
    }
    atomicAdd(&pooled[g * HO + 2 * t], al);
    atomicAdd(&pooled[g * HO + 2 * t + 1], ah);
}

// ---- K6: FC over pooled means ----
__global__ __launch_bounds__(64) void fc_k(const float* __restrict__ pooled,
                                           const int* __restrict__ gstart,
                                           const float* __restrict__ fc_w,
                                           const float* __restrict__ fc_b,
                                           float* __restrict__ out) {
    int g = blockIdx.x;
    int lane = threadIdx.x;
    float a0 = 0.f, a1 = 0.f;
#pragma unroll
    for (int k = 0; k < 6; k++) {
        int c = lane + 64 * k;
        float pv = pooled[g * HO + c];
        a0 += pv * fc_w[c * 2 + 0];
        a1 += pv * fc_w[c * 2 + 1];
    }
#pragma unroll
    for (int off = 32; off > 0; off >>= 1) {
        a0 += __shfl_down(a0, off);
        a1 += __shfl_down(a1, off);
    }
    if (lane == 0) {
        float cnt = fmaxf((float)(gstart[g + 1] - gstart[g]), 1.0f);
        out[g * 2 + 0] = a0 / cnt + fc_b[0];
        out[g * 2 + 1] = a1 / cnt + fc_b[1];
    }
}

extern "C" void kernel_launch(void* const* d_in, const int* in_sizes, int n_in,
                              void* d_out, int out_size, void* d_ws, size_t ws_size,
                              hipStream_t stream) {
    const float* x       = (const float*)d_in[0];
    const int*   ei      = (const int*)d_in[1];
    const int*   batch   = (const int*)d_in[2];
    const float* W       = (const float*)d_in[3];
    const float* att_src = (const float*)d_in[4];
    const float* att_dst = (const float*)d_in[5];
    const float* bias    = (const float*)d_in[6];
    const float* fc_w    = (const float*)d_in[7];
    const float* fc_b    = (const float*)d_in[8];
    float* out = (float*)d_out;

    const int N = in_sizes[2];
    const int E = in_sizes[1] / 2;
    const int ET = E + N;

    char* p = (char*)d_ws;
    auto alloc = [&](size_t bytes) -> char* {
        char* r = p;
        p += (bytes + 255) & ~(size_t)255;
        return r;
    };
    short*         wbt    = (short*)alloc((size_t)HO * F_IN * 2);
    short*         wat    = (short*)alloc((size_t)16 * F_IN * 2);
    short*         xb     = (short*)alloc((size_t)N * F_IN * 2);
    unsigned char* hc     = (unsigned char*)alloc((size_t)N * 384);
    unsigned*      outb   = (unsigned*)alloc((size_t)N * 192 * 4);
    float*         ni     = (float*)alloc((size_t)N * 8 * 4);
    float*         a_dst  = (float*)alloc((size_t)N * 3 * 4);
    char*          zstart = p;
    int*           count  = (int*)alloc((size_t)N * 4);              // zeroed
    float*         pooled = (float*)alloc((size_t)NGRAPH * HO * 4);  // zeroed
    size_t         zbytes = (size_t)(p - zstart);
    int*           offsets = (int*)alloc((size_t)N * 4);
    int*           rank    = (int*)alloc((size_t)ET * 4);
    int*           bsums   = (int*)alloc(4096);
    int*           gstart  = (int*)alloc(1024);
    int*           csr_src = (int*)alloc((size_t)ET * 4);

    hipMemsetAsync(zstart, 0, zbytes, stream);

    int NBc = (ET + 255) / 256;
    int NXc = (int)(((size_t)N * F_IN + 2047) / 2048);
    misc_k<<<NBc + 386 + NXc, 256, 0, stream>>>(ei, W, batch, x, att_src, att_dst,
                                                count, rank, wbt, wat, xb, gstart,
                                                NBc, E, N);
    gemm_att<<<(N + 31) / 32, 256, 0, stream>>>(xb, wbt, wat, hc, ni, a_dst, N);
    int NB = (N + 255) / 256;
    scan_a<<<NB, 256, 0, stream>>>(count, offsets, bsums, N);
    scan_b<<<1, 256, 0, stream>>>(bsums, NB);
    scan_c<<<NB, 256, 0, stream>>>(offsets, bsums, N);
    scatter_k<<<(ET + 255) / 256, 256, 0, stream>>>(ei, rank, offsets, csr_src, E, N);
    aggregate_k<<<(N + 3) / 4, 256, 0, stream>>>((const unsigned*)hc, csr_src, offsets,
                                                 count, ni, a_dst, bias, outb, N);
    dim3 pg(NGRAPH, 8);
    pool_k<<<pg, 192, 0, stream>>>(outb, gstart, pooled);
    fc_k<<<NGRAPH, 64, 0, stream>>>(pooled, gstart, fc_w, fc_b, out);

    (void)n_in; (void)out_size; (void)ws_size;
}